// Round 8
// baseline (404.735 us; speedup 1.0000x reference)
//
#include <hip/hip_runtime.h>
#include <math.h>

#define BB 2
#define LL 2048
#define DD 1024
#define HH 16
#define DH 64
#define HID 4096
#define MROWS (BB*LL)   // 4096

typedef __attribute__((ext_vector_type(8))) short bf16x8;
typedef __attribute__((ext_vector_type(4))) float f32x4;

__device__ __forceinline__ unsigned short f2bf(float f) {
    unsigned u = __builtin_bit_cast(unsigned, f);
    unsigned r = u + 0x7fffu + ((u >> 16) & 1u);
    return (unsigned short)(r >> 16);
}

__device__ __forceinline__ void ldsload16(const void* g, void* l) {
    __builtin_amdgcn_global_load_lds(
        (const __attribute__((address_space(1))) unsigned int*)g,
        (__attribute__((address_space(3))) unsigned int*)l,
        16, 0, 0);
}

// ------------------------------------------------- weight convert+transpose
// in: fp32 [K][N] row-major  ->  out: bf16 [N][K] row-major
__global__ __launch_bounds__(256) void convT_kernel(const float* __restrict__ in,
                                                    unsigned short* __restrict__ out,
                                                    int K, int N) {
    __shared__ float tile[64][65];
    int kt = blockIdx.y << 6, nt = blockIdx.x << 6;
    int t = threadIdx.x;
    int tr = t >> 4;            // 0..15
    int tc = (t & 15) << 2;     // 0,4,...,60
    #pragma unroll
    for (int i = 0; i < 4; ++i) {
        float4 v = *reinterpret_cast<const float4*>(&in[(size_t)(kt + i*16 + tr) * N + nt + tc]);
        tile[i*16 + tr][tc+0] = v.x;
        tile[i*16 + tr][tc+1] = v.y;
        tile[i*16 + tr][tc+2] = v.z;
        tile[i*16 + tr][tc+3] = v.w;
    }
    __syncthreads();
    #pragma unroll
    for (int i = 0; i < 4; ++i) {
        int n = i*16 + tr;
        ushort4 o4;
        o4.x = f2bf(tile[tc+0][n]);
        o4.y = f2bf(tile[tc+1][n]);
        o4.z = f2bf(tile[tc+2][n]);
        o4.w = f2bf(tile[tc+3][n]);
        *reinterpret_cast<ushort4*>(&out[(size_t)(nt + n) * K + kt + tc]) = o4;
    }
}

// ---------------------------------------------------------------- LayerNorm
// fp32 in -> bf16 out
__global__ __launch_bounds__(256) void ln_kernel(const float* __restrict__ in,
                                                 const float* __restrict__ w,
                                                 const float* __restrict__ b,
                                                 unsigned short* __restrict__ out) {
    int row = blockIdx.x;
    const float* x = in + (size_t)row * DD;
    unsigned short* o = out + (size_t)row * DD;
    int t = threadIdx.x;
    float4 v = reinterpret_cast<const float4*>(x)[t];
    float s  = v.x + v.y + v.z + v.w;
    float ss = v.x*v.x + v.y*v.y + v.z*v.z + v.w*v.w;
    #pragma unroll
    for (int off = 32; off > 0; off >>= 1) {
        s  += __shfl_down(s,  off, 64);
        ss += __shfl_down(ss, off, 64);
    }
    __shared__ float red[8];
    int wid = t >> 6, lane = t & 63;
    if (lane == 0) { red[wid] = s; red[4 + wid] = ss; }
    __syncthreads();
    if (t == 0) {
        float S  = red[0] + red[1] + red[2] + red[3];
        float SS = red[4] + red[5] + red[6] + red[7];
        float mean = S / DD;
        float var  = SS / DD - mean * mean;
        red[0] = mean;
        red[1] = rsqrtf(var + 1e-5f);
    }
    __syncthreads();
    float mean = red[0], rstd = red[1];
    float4 wv = reinterpret_cast<const float4*>(w)[t];
    float4 bv = reinterpret_cast<const float4*>(b)[t];
    ushort4 ov;
    ov.x = f2bf((v.x - mean) * rstd * wv.x + bv.x);
    ov.y = f2bf((v.y - mean) * rstd * wv.y + bv.y);
    ov.z = f2bf((v.z - mean) * rstd * wv.z + bv.z);
    ov.w = f2bf((v.w - mean) * rstd * wv.w + bv.w);
    reinterpret_cast<ushort4*>(o)[t] = ov;
}

// --------------------------------------- LayerNorm fused with partial-add
// y += part (written back), then h = LN(y) -> bf16 out
__global__ __launch_bounds__(256) void ln_fuse_kernel(float* __restrict__ y,
                                                      const float* __restrict__ part,
                                                      const float* __restrict__ w,
                                                      const float* __restrict__ b,
                                                      unsigned short* __restrict__ out) {
    int row = blockIdx.x;
    float* xr = y + (size_t)row * DD;
    const float* pr = part + (size_t)row * DD;
    unsigned short* o = out + (size_t)row * DD;
    int t = threadIdx.x;
    float4 v  = reinterpret_cast<float4*>(xr)[t];
    float4 pv = reinterpret_cast<const float4*>(pr)[t];
    v.x += pv.x; v.y += pv.y; v.z += pv.z; v.w += pv.w;
    reinterpret_cast<float4*>(xr)[t] = v;
    float s  = v.x + v.y + v.z + v.w;
    float ss = v.x*v.x + v.y*v.y + v.z*v.z + v.w*v.w;
    #pragma unroll
    for (int off = 32; off > 0; off >>= 1) {
        s  += __shfl_down(s,  off, 64);
        ss += __shfl_down(ss, off, 64);
    }
    __shared__ float red[8];
    int wid = t >> 6, lane = t & 63;
    if (lane == 0) { red[wid] = s; red[4 + wid] = ss; }
    __syncthreads();
    if (t == 0) {
        float S  = red[0] + red[1] + red[2] + red[3];
        float SS = red[4] + red[5] + red[6] + red[7];
        float mean = S / DD;
        float var  = SS / DD - mean * mean;
        red[0] = mean;
        red[1] = rsqrtf(var + 1e-5f);
    }
    __syncthreads();
    float mean = red[0], rstd = red[1];
    float4 wv = reinterpret_cast<const float4*>(w)[t];
    float4 bv = reinterpret_cast<const float4*>(b)[t];
    ushort4 ov;
    ov.x = f2bf((v.x - mean) * rstd * wv.x + bv.x);
    ov.y = f2bf((v.y - mean) * rstd * wv.y + bv.y);
    ov.z = f2bf((v.z - mean) * rstd * wv.z + bv.z);
    ov.w = f2bf((v.w - mean) * rstd * wv.w + bv.w);
    reinterpret_cast<ushort4*>(o)[t] = ov;
}

// ------------------------------------------------------------- y += part
__global__ __launch_bounds__(256) void fadd_kernel(float* __restrict__ y,
                                                   const float* __restrict__ p, int n4) {
    int i = blockIdx.x * 256 + threadIdx.x;
    int stride = gridDim.x * 256;
    for (; i < n4; i += stride) {
        float4 a = reinterpret_cast<float4*>(y)[i];
        float4 b = reinterpret_cast<const float4*>(p)[i];
        a.x += b.x; a.y += b.y; a.z += b.z; a.w += b.w;
        reinterpret_cast<float4*>(y)[i] = a;
    }
}

// ---------------------------------------------- MFMA GEMM (128x128, split-K)
// For N=1024 GEMMs. grid = SK * (M/128)*(N/128); 2 blocks/CU when SK=2.
// split 0: C = acc + bias + res (fp32). split 1: part = acc (raw fp32).
// Triple-buffered, 2-deep prefetch, counted vmcnt. Fragment-linear LDS.
template<int SK>
__global__ __launch_bounds__(256) void mgemm_sk(
    const unsigned short* __restrict__ A,
    const unsigned short* __restrict__ WT,
    const float* __restrict__ bias,
    const float* __restrict__ res,
    float* __restrict__ C,
    float* __restrict__ part,
    int M, int N, int K, int nbx)
{
    __shared__ __align__(16) unsigned char smem[49152];   // 3 x (A 8KB + B 8KB)
    int half = gridDim.x / SK;
    int bid = blockIdx.x;
    int sk = (SK > 1) ? (bid / half) : 0;
    int rel = bid - sk * half;
    int cpx = half >> 3;                                  // half %8 == 0
    int swz = (rel & 7) * cpx + (rel >> 3);               // XCD-aware swizzle
    int bn = (swz % nbx) * 128;
    int bm = (swz / nbx) * 128;
    int Keff = K / SK;
    int t = threadIdx.x, lane = t & 63, w = t >> 6;
    int wr = w >> 1, wc = w & 1;
    int l15 = lane & 15, l4 = lane >> 4;

    const unsigned short* Ap = A  + (size_t)(bm + w*32 + l15) * K + sk*Keff + 8*l4;
    const unsigned short* Bp = WT + (size_t)(bn + w*32 + l15) * K + sk*Keff + 8*l4;
    unsigned stoff = w*2048 + lane*16;

    f32x4 acc[4][4] = {};
    int nk = Keff >> 5;

    unsigned char* pb0 = smem;
    unsigned char* pb1 = smem + 16384;
    unsigned char* pb2 = smem + 32768;

    auto stage = [&](unsigned char* bs) {
        ldsload16(Ap,        bs + stoff);
        ldsload16(Ap + 16*K, bs + stoff + 1024);
        ldsload16(Bp,        bs + 8192 + stoff);
        ldsload16(Bp + 16*K, bs + 8192 + stoff + 1024);
        Ap += 32; Bp += 32;
    };

    stage(pb0);
    stage(pb1);

    for (int k = 0; k < nk; ++k) {
        if (k + 2 < nk) {
            stage(pb2);
            asm volatile("s_waitcnt vmcnt(8)\ns_barrier" ::: "memory");
        } else if (k + 2 == nk) {
            asm volatile("s_waitcnt vmcnt(4)\ns_barrier" ::: "memory");
        } else {
            asm volatile("s_waitcnt vmcnt(0)\ns_barrier" ::: "memory");
        }
        unsigned char* Asb = pb0;
        unsigned char* Bsb = pb0 + 8192;
        bf16x8 af[4], bfr[4];
        #pragma unroll
        for (int mm = 0; mm < 4; ++mm)
            af[mm] = *reinterpret_cast<const bf16x8*>(Asb + (wr*4 + mm)*1024 + lane*16);
        #pragma unroll
        for (int nn = 0; nn < 4; ++nn)
            bfr[nn] = *reinterpret_cast<const bf16x8*>(Bsb + (wc*4 + nn)*1024 + lane*16);
        #pragma unroll
        for (int mm = 0; mm < 4; ++mm)
            #pragma unroll
            for (int nn = 0; nn < 4; ++nn)
                acc[mm][nn] = __builtin_amdgcn_mfma_f32_16x16x32_bf16(af[mm], bfr[nn], acc[mm][nn], 0, 0, 0);
        asm volatile("s_waitcnt lgkmcnt(0)\ns_barrier" ::: "memory");
        unsigned char* tp = pb0; pb0 = pb1; pb1 = pb2; pb2 = tp;
    }

    #pragma unroll
    for (int mm = 0; mm < 4; ++mm) {
        int row0 = bm + wr*64 + mm*16 + l4*4;
        #pragma unroll
        for (int nn = 0; nn < 4; ++nn) {
            int col = bn + wc*64 + nn*16 + l15;
            float bi = bias[col];
            #pragma unroll
            for (int r = 0; r < 4; ++r) {
                size_t idx = (size_t)(row0 + r) * N + col;
                if (sk == 0) {
                    C[idx] = acc[mm][nn][r] + bi + res[idx];
                } else {
                    part[idx] = acc[mm][nn][r];
                }
            }
        }
    }
}

// ------------------------------------------------------- MFMA GEMM (256x256)
// 8 waves (2Mx4N), BK=64, double-buffered 128KiB LDS, counted vmcnt(8).
// EPI: 1 = GELU -> bf16; 3 = qkv (Q/K bf16 row-major, V -> vt transposed).
template<int EPI>
__global__ __launch_bounds__(512, 2) void mgemm256(
    const unsigned short* __restrict__ A,
    const unsigned short* __restrict__ WT,
    const float* __restrict__ bias,
    void* Cv,
    unsigned short* __restrict__ vt,
    int M, int N, int K, int nbx)
{
    __shared__ __align__(16) unsigned char smem[131072];  // 2 x (A 32KB + B 32KB)
    int bid = blockIdx.x;
    int nwg = gridDim.x;
    int cpx = nwg >> 3;                                   // grids %8 == 0
    int swz = (bid & 7) * cpx + (bid >> 3);               // XCD-aware swizzle
    int bn = (swz % nbx) * 256;
    int bm = (swz / nbx) * 256;
    int t = threadIdx.x, lane = t & 63, w = t >> 6;       // w: 0..7
    int wr = w >> 2, wc = w & 3;                          // 2 x 4 waves
    int l15 = lane & 15, l4 = lane >> 4;

    const unsigned short* Ap0 = A  + (size_t)(bm + w*16 + l15) * K + 8*l4;
    const unsigned short* Ap1 = Ap0 + (size_t)128 * K;
    const unsigned short* Bp0 = WT + (size_t)(bn + w*16 + l15) * K + 8*l4;
    const unsigned short* Bp1 = Bp0 + (size_t)128 * K;
    unsigned aoff = w*1024 + lane*16;
    int koff = 0;

    f32x4 acc[8][4] = {};
    int nk = K >> 6;

    auto stage = [&](int buf) {
        unsigned char* Asb = smem + (buf << 16);
        unsigned char* Bsb = Asb + 32768;
        ldsload16(Ap0 + koff,      Asb + aoff);
        ldsload16(Ap1 + koff,      Asb + aoff + 8192);
        ldsload16(Ap0 + koff + 32, Asb + aoff + 16384);
        ldsload16(Ap1 + koff + 32, Asb + aoff + 24576);
        ldsload16(Bp0 + koff,      Bsb + aoff);
        ldsload16(Bp1 + koff,      Bsb + aoff + 8192);
        ldsload16(Bp0 + koff + 32, Bsb + aoff + 16384);
        ldsload16(Bp1 + koff + 32, Bsb + aoff + 24576);
        koff += 64;
    };

    stage(0);
    for (int k = 0; k < nk; ++k) {
        if (k + 1 < nk) {
            stage((k + 1) & 1);
            asm volatile("s_waitcnt vmcnt(8)\ns_barrier" ::: "memory");
        } else {
            asm volatile("s_waitcnt vmcnt(0)\ns_barrier" ::: "memory");
        }
        unsigned char* Asb = smem + ((k & 1) << 16);
        unsigned char* Bsb = Asb + 32768;
        #pragma unroll
        for (int kc = 0; kc < 2; ++kc) {
            bf16x8 af[8], bfr[4];
            #pragma unroll
            for (int mm = 0; mm < 8; ++mm)
                af[mm] = *reinterpret_cast<const bf16x8*>(Asb + kc*16384 + (wr*8 + mm)*1024 + lane*16);
            #pragma unroll
            for (int nn = 0; nn < 4; ++nn)
                bfr[nn] = *reinterpret_cast<const bf16x8*>(Bsb + kc*16384 + (wc*4 + nn)*1024 + lane*16);
            #pragma unroll
            for (int mm = 0; mm < 8; ++mm)
                #pragma unroll
                for (int nn = 0; nn < 4; ++nn)
                    acc[mm][nn] = __builtin_amdgcn_mfma_f32_16x16x32_bf16(af[mm], bfr[nn], acc[mm][nn], 0, 0, 0);
        }
        asm volatile("s_waitcnt lgkmcnt(0)\ns_barrier" ::: "memory");
    }

    bool isv = (EPI == 3) && (bn >= 2048);
    #pragma unroll
    for (int mm = 0; mm < 8; ++mm) {
        int row0 = bm + wr*128 + mm*16 + l4*4;
        #pragma unroll
        for (int nn = 0; nn < 4; ++nn) {
            int col = bn + wc*64 + nn*16 + l15;
            float bi = bias[col];
            #pragma unroll
            for (int r = 0; r < 4; ++r) {
                float v = acc[mm][nn][r] + bi;
                int row = row0 + r;
                size_t idx = (size_t)row * N + col;
                if (EPI == 1) {
                    v = 0.5f * v * (1.0f + erff(v * 0.70710678118654752f));
                    ((unsigned short*)Cv)[idx] = f2bf(v);
                } else { // EPI == 3
                    if (!isv) {
                        ((unsigned short*)Cv)[idx] = f2bf(v);
                    } else {
                        int bb = row >> 11, l = row & 2047;
                        int c2 = col - 2048, hh = c2 >> 6, dd = c2 & 63;
                        vt[((((size_t)(bb*HH + hh)*2 + (l & 1))*64 + dd) << 10) + (l >> 1)] = f2bf(v);
                    }
                }
            }
        }
    }
}

// ---------------------------------------------------------------- Attention
// Dilation-2 causal window == 2 independent causal sliding-window attentions
// (per parity), compressed length 1024, window 128 (+self). MFMA, 1 wave/blk.
__global__ __launch_bounds__(64, 1) void mattn(
    const unsigned short* __restrict__ qkvb,  // [4096][3072] bf16
    const unsigned short* __restrict__ vt,    // [b][h][p][64][1024] bf16
    unsigned short* __restrict__ o)           // [4096][1024] bf16
{
    __shared__ __align__(16) unsigned char PlB[8192];     // P tile, swizzled
    int qt = blockIdx.x, p = blockIdx.y, bh = blockIdx.z;
    int b = bh >> 4, h = bh & 15;
    int lane = threadIdx.x;
    int l15 = lane & 15, l4 = lane >> 4;

    bf16x8 qf[4][2];
    #pragma unroll
    for (int qb = 0; qb < 4; ++qb) {
        int tq = qt*64 + qb*16 + l15;
        const unsigned short* qr = qkvb + (size_t)(b*LL + 2*tq + p)*3072 + h*64 + 8*l4;
        qf[qb][0] = *reinterpret_cast<const bf16x8*>(qr);
        qf[qb][1] = *reinterpret_cast<const bf16x8*>(qr + 32);
    }

    float mreg[4], lreg[4];
    #pragma unroll
    for (int qb = 0; qb < 4; ++qb) { mreg[qb] = -1e30f; lreg[qb] = 0.f; }
    f32x4 oac[4][4] = {};   // [mt=d-tile][qb], O^T layout

    const unsigned short* vbase = vt + ((size_t)((b*HH + h)*2 + p) << 16);

    int kt0 = qt - 2; if (kt0 < 0) kt0 = 0;
    for (int kt = kt0; kt <= qt; ++kt) {
        bf16x8 kf[4][2], vf[4][2];
        #pragma unroll
        for (int kb = 0; kb < 4; ++kb) {
            const unsigned short* kr = qkvb + (size_t)(b*LL + 2*(kt*64 + kb*16 + l15) + p)*3072 + 1024 + h*64 + 8*l4;
            kf[kb][0] = *reinterpret_cast<const bf16x8*>(kr);
            kf[kb][1] = *reinterpret_cast<const bf16x8*>(kr + 32);
        }
        #pragma unroll
        for (int mt = 0; mt < 4; ++mt) {
            const unsigned short* vr = vbase + (mt*16 + l15)*1024 + kt*64 + 8*l4;
            vf[mt][0] = *reinterpret_cast<const bf16x8*>(vr);
            vf[mt][1] = *reinterpret_cast<const bf16x8*>(vr + 32);
        }
        f32x4 st[4][4];
        #pragma unroll
        for (int kb = 0; kb < 4; ++kb)
            #pragma unroll
            for (int qb = 0; qb < 4; ++qb) {
                f32x4 z = {0.f, 0.f, 0.f, 0.f};
                z = __builtin_amdgcn_mfma_f32_16x16x32_bf16(kf[kb][0], qf[qb][0], z, 0, 0, 0);
                st[kb][qb] = __builtin_amdgcn_mfma_f32_16x16x32_bf16(kf[kb][1], qf[qb][1], z, 0, 0, 0);
            }
        #pragma unroll
        for (int qb = 0; qb < 4; ++qb) {
            int tq = qt*64 + qb*16 + l15;
            int q = qb*16 + l15;
            float tmax = -1e30f;
            #pragma unroll
            for (int kb = 0; kb < 4; ++kb)
                #pragma unroll
                for (int r = 0; r < 4; ++r) {
                    int kc = kt*64 + kb*16 + 4*l4 + r;
                    float sv = st[kb][qb][r] * 0.125f;
                    sv = (kc + 128 >= tq && kc <= tq) ? sv : -1e30f;
                    st[kb][qb][r] = sv;
                    tmax = fmaxf(tmax, sv);
                }
            tmax = fmaxf(tmax, __shfl_xor(tmax, 16, 64));
            tmax = fmaxf(tmax, __shfl_xor(tmax, 32, 64));
            float newm = fmaxf(mreg[qb], tmax);
            float corr = __expf(mreg[qb] - newm);
            mreg[qb] = newm;
            float ps = 0.f;
            #pragma unroll
            for (int kb = 0; kb < 4; ++kb) {
                float p0 = __expf(st[kb][qb][0] - newm);
                float p1 = __expf(st[kb][qb][1] - newm);
                float p2 = __expf(st[kb][qb][2] - newm);
                float p3 = __expf(st[kb][qb][3] - newm);
                ps += (p0 + p1) + (p2 + p3);
                unsigned lo = (unsigned)f2bf(p0) | ((unsigned)f2bf(p1) << 16);
                unsigned hi = (unsigned)f2bf(p2) | ((unsigned)f2bf(p3) << 16);
                unsigned byteoff = ((unsigned)(q << 7) + (unsigned)(kb*32 + 8*l4)) ^ ((unsigned)(q & 7) << 4);
                *reinterpret_cast<uint2*>(PlB + byteoff) = make_uint2(lo, hi);
            }
            ps += __shfl_xor(ps, 16, 64);
            ps += __shfl_xor(ps, 32, 64);
            lreg[qb] = lreg[qb] * corr + ps;
            #pragma unroll
            for (int mt = 0; mt < 4; ++mt) {
                oac[mt][qb][0] *= corr; oac[mt][qb][1] *= corr;
                oac[mt][qb][2] *= corr; oac[mt][qb][3] *= corr;
            }
        }
        #pragma unroll
        for (int c = 0; c < 2; ++c)
            #pragma unroll
            for (int qb = 0; qb < 4; ++qb) {
                int q = qb*16 + l15;
                unsigned rb = ((unsigned)(q << 7) + (unsigned)(c*64 + 16*l4)) ^ ((unsigned)(q & 7) << 4);
                bf16x8 pf = *reinterpret_cast<const bf16x8*>(PlB + rb);
                #pragma unroll
                for (int mt = 0; mt < 4; ++mt)
                    oac[mt][qb] = __builtin_amdgcn_mfma_f32_16x16x32_bf16(vf[mt][c], pf, oac[mt][qb], 0, 0, 0);
            }
    }

    #pragma unroll
    for (int qb = 0; qb < 4; ++qb) {
        float inv = 1.f / lreg[qb];
        int tq = qt*64 + qb*16 + l15;
        unsigned short* orow = o + (size_t)(b*LL + 2*tq + p)*DD + h*64;
        #pragma unroll
        for (int mt = 0; mt < 4; ++mt) {
            int d0 = mt*16 + 4*l4;
            ushort4 o4;
            o4.x = f2bf(oac[mt][qb][0] * inv);
            o4.y = f2bf(oac[mt][qb][1] * inv);
            o4.z = f2bf(oac[mt][qb][2] * inv);
            o4.w = f2bf(oac[mt][qb][3] * inv);
            *reinterpret_cast<ushort4*>(orow + d0) = o4;
        }
    }
}

// ---------------------------------------------------------------- launch
extern "C" void kernel_launch(void* const* d_in, const int* in_sizes, int n_in,
                              void* d_out, int out_size, void* d_ws, size_t ws_size,
                              hipStream_t stream) {
    const float* x      = (const float*)d_in[0];
    const float* n1w    = (const float*)d_in[1];
    const float* n1b    = (const float*)d_in[2];
    const float* qkv_w  = (const float*)d_in[3];
    const float* qkv_b  = (const float*)d_in[4];
    const float* out_w  = (const float*)d_in[5];
    const float* out_b  = (const float*)d_in[6];
    const float* n2w    = (const float*)d_in[7];
    const float* n2b    = (const float*)d_in[8];
    const float* ffn_w1 = (const float*)d_in[9];
    const float* ffn_b1 = (const float*)d_in[10];
    const float* ffn_w2 = (const float*)d_in[11];
    const float* ffn_b2 = (const float*)d_in[12];

    unsigned char* wsb = (unsigned char*)d_ws;
    const size_t MB = 1024 * 1024;

    // ws layout (80MB):
    //  [0,24)  qkvb bf16  -> after attn: part1a fp32 [0,16) -> mid bf16 [0,32)
    //  [24,32) vt bf16    -/
    //  [32,40) o_b bf16   -> after out-proj: part1b fp32 [32,48)
    //  [40,48) xn bf16    -/
    //  [48,56) hbuf bf16
    //  [56,80) weights bf16 transposed (qkvT 6, outT 2, w1T 8, w2T 8)
    unsigned short* qkvb  = (unsigned short*)wsb;
    unsigned short* vt    = (unsigned short*)(wsb + 24*MB);
    unsigned short* mid   = (unsigned short*)wsb;
    float*          part1a= (float*)wsb;                    // out-proj split-1 partial
    unsigned short* o_b   = (unsigned short*)(wsb + 32*MB);
    float*          part1b= (float*)(wsb + 32*MB);          // ffn2 split-1 partial
    unsigned short* xn    = (unsigned short*)(wsb + 40*MB);
    unsigned short* hbuf  = (unsigned short*)(wsb + 48*MB);
    unsigned short* qkvT  = (unsigned short*)(wsb + 56*MB);
    unsigned short* outT  = (unsigned short*)(wsb + 62*MB);
    unsigned short* w1T   = (unsigned short*)(wsb + 64*MB);
    unsigned short* w2T   = (unsigned short*)(wsb + 72*MB);
    float*          y     = (float*)d_out;              // d_out doubles as y

    // 0. weight convert+transpose  fp32[K][N] -> bf16[N][K]
    convT_kernel<<<dim3(3*DD/64, DD/64), 256, 0, stream>>>(qkv_w,  qkvT, DD,  3*DD);
    convT_kernel<<<dim3(DD/64,   DD/64), 256, 0, stream>>>(out_w,  outT, DD,  DD);
    convT_kernel<<<dim3(HID/64,  DD/64), 256, 0, stream>>>(ffn_w1, w1T,  DD,  HID);
    convT_kernel<<<dim3(DD/64,  HID/64), 256, 0, stream>>>(ffn_w2, w2T,  HID, DD);

    // 1. xn = LN(x)                        (bf16)
    ln_kernel<<<MROWS, 256, 0, stream>>>(x, n1w, n1b, xn);
    // 2. qkv = xn @ qkv_w + qkv_b          (Q/K bf16 rowmajor, V -> vt)  [256²]
    mgemm256<3><<<(3*DD/256)*(MROWS/256), 512, 0, stream>>>(
        xn, qkvT, qkv_b, qkvb, vt, MROWS, 3*DD, DD, 3*DD/256);
    // 3. o = dilated-window attention      (bf16, MFMA)
    mattn<<<dim3(16, 2, BB*HH), 64, 0, stream>>>(qkvb, vt, o_b);
    // 4. y(sk0) = x + o @ out_w + out_b ; part1a(sk1)   [128² split-K=2]
    mgemm_sk<2><<<2*(DD/128)*(MROWS/128), 256, 0, stream>>>(
        o_b, outT, out_b, x, y, part1a, MROWS, DD, DD, DD/128);
    // 5. y += part1a; h = LN(y)            (fused, bf16)
    ln_fuse_kernel<<<MROWS, 256, 0, stream>>>(y, part1a, n2w, n2b, hbuf);
    // 6. mid = gelu(h @ ffn_w1 + b1)       (bf16)  [256²]
    mgemm256<1><<<(HID/256)*(MROWS/256), 512, 0, stream>>>(
        hbuf, w1T, ffn_b1, mid, nullptr, MROWS, HID, DD, HID/256);
    // 7. y(sk0) = y + mid @ ffn_w2 + b2 ; part1b(sk1)   [128² split-K=2]
    mgemm_sk<2><<<2*(DD/128)*(MROWS/128), 256, 0, stream>>>(
        mid, w2T, ffn_b2, y, y, part1b, MROWS, DD, HID, DD/128);
    // 8. y += part1b                       (final output)
    fadd_kernel<<<2048, 256, 0, stream>>>(y, part1b, MROWS*DD/4);
}

// Round 10
// 389.180 us; speedup vs baseline: 1.0400x; 1.0400x over previous
//
#include <hip/hip_runtime.h>
#include <math.h>

#define BB 2
#define LL 2048
#define DD 1024
#define HH 16
#define DH 64
#define HID 4096
#define MROWS (BB*LL)   // 4096

typedef __attribute__((ext_vector_type(8))) short bf16x8;
typedef __attribute__((ext_vector_type(4))) float f32x4;

__device__ __forceinline__ unsigned short f2bf(float f) {
    unsigned u = __builtin_bit_cast(unsigned, f);
    unsigned r = u + 0x7fffu + ((u >> 16) & 1u);
    return (unsigned short)(r >> 16);
}

__device__ __forceinline__ void ldsload16(const void* g, void* l) {
    __builtin_amdgcn_global_load_lds(
        (const __attribute__((address_space(1))) unsigned int*)g,
        (__attribute__((address_space(3))) unsigned int*)l,
        16, 0, 0);
}

// ------------------------------------------------- weight convert+transpose
// in: fp32 [K][N] row-major  ->  out: bf16 [N][K] row-major
__global__ __launch_bounds__(256) void convT_kernel(const float* __restrict__ in,
                                                    unsigned short* __restrict__ out,
                                                    int K, int N) {
    __shared__ float tile[64][65];
    int kt = blockIdx.y << 6, nt = blockIdx.x << 6;
    int t = threadIdx.x;
    int tr = t >> 4;            // 0..15
    int tc = (t & 15) << 2;     // 0,4,...,60
    #pragma unroll
    for (int i = 0; i < 4; ++i) {
        float4 v = *reinterpret_cast<const float4*>(&in[(size_t)(kt + i*16 + tr) * N + nt + tc]);
        tile[i*16 + tr][tc+0] = v.x;
        tile[i*16 + tr][tc+1] = v.y;
        tile[i*16 + tr][tc+2] = v.z;
        tile[i*16 + tr][tc+3] = v.w;
    }
    __syncthreads();
    #pragma unroll
    for (int i = 0; i < 4; ++i) {
        int n = i*16 + tr;
        ushort4 o4;
        o4.x = f2bf(tile[tc+0][n]);
        o4.y = f2bf(tile[tc+1][n]);
        o4.z = f2bf(tile[tc+2][n]);
        o4.w = f2bf(tile[tc+3][n]);
        *reinterpret_cast<ushort4*>(&out[(size_t)(nt + n) * K + kt + tc]) = o4;
    }
}

// ---------------------------------------------------------------- LayerNorm
// fp32 in -> bf16 out
__global__ __launch_bounds__(256) void ln_kernel(const float* __restrict__ in,
                                                 const float* __restrict__ w,
                                                 const float* __restrict__ b,
                                                 unsigned short* __restrict__ out) {
    int row = blockIdx.x;
    const float* x = in + (size_t)row * DD;
    unsigned short* o = out + (size_t)row * DD;
    int t = threadIdx.x;
    float4 v = reinterpret_cast<const float4*>(x)[t];
    float s  = v.x + v.y + v.z + v.w;
    float ss = v.x*v.x + v.y*v.y + v.z*v.z + v.w*v.w;
    #pragma unroll
    for (int off = 32; off > 0; off >>= 1) {
        s  += __shfl_down(s,  off, 64);
        ss += __shfl_down(ss, off, 64);
    }
    __shared__ float red[8];
    int wid = t >> 6, lane = t & 63;
    if (lane == 0) { red[wid] = s; red[4 + wid] = ss; }
    __syncthreads();
    if (t == 0) {
        float S  = red[0] + red[1] + red[2] + red[3];
        float SS = red[4] + red[5] + red[6] + red[7];
        float mean = S / DD;
        float var  = SS / DD - mean * mean;
        red[0] = mean;
        red[1] = rsqrtf(var + 1e-5f);
    }
    __syncthreads();
    float mean = red[0], rstd = red[1];
    float4 wv = reinterpret_cast<const float4*>(w)[t];
    float4 bv = reinterpret_cast<const float4*>(b)[t];
    ushort4 ov;
    ov.x = f2bf((v.x - mean) * rstd * wv.x + bv.x);
    ov.y = f2bf((v.y - mean) * rstd * wv.y + bv.y);
    ov.z = f2bf((v.z - mean) * rstd * wv.z + bv.z);
    ov.w = f2bf((v.w - mean) * rstd * wv.w + bv.w);
    reinterpret_cast<ushort4*>(o)[t] = ov;
}

// ------------------------------------------------------- MFMA GEMM (128x128)
// For N=1024 GEMMs (grid stays 256 blocks). EPI 2 = fp32 out + res.
// Triple-buffered, 2-deep prefetch, counted vmcnt. Fragment-linear LDS.
template<int EPI>
__global__ __launch_bounds__(256) void mgemm(
    const unsigned short* __restrict__ A,
    const unsigned short* __restrict__ WT,
    const float* __restrict__ bias,
    const float* res, void* Cv,
    int M, int N, int K, int nbx)
{
    __shared__ __align__(16) unsigned char smem[49152];   // 3 x (A 8KB + B 8KB)
    int bid = blockIdx.x;
    int nwg = gridDim.x;
    int cpx = nwg >> 3;                                   // grids %8 == 0
    int swz = (bid & 7) * cpx + (bid >> 3);               // XCD-aware swizzle
    int bn = (swz % nbx) * 128;
    int bm = (swz / nbx) * 128;
    int t = threadIdx.x, lane = t & 63, w = t >> 6;
    int wr = w >> 1, wc = w & 1;
    int l15 = lane & 15, l4 = lane >> 4;

    const unsigned short* Ap = A  + (size_t)(bm + w*32 + l15) * K + 8*l4;
    const unsigned short* Bp = WT + (size_t)(bn + w*32 + l15) * K + 8*l4;
    unsigned stoff = w*2048 + lane*16;

    f32x4 acc[4][4] = {};
    int nk = K >> 5;

    unsigned char* pb0 = smem;
    unsigned char* pb1 = smem + 16384;
    unsigned char* pb2 = smem + 32768;

    auto stage = [&](unsigned char* bs) {
        ldsload16(Ap,        bs + stoff);
        ldsload16(Ap + 16*K, bs + stoff + 1024);
        ldsload16(Bp,        bs + 8192 + stoff);
        ldsload16(Bp + 16*K, bs + 8192 + stoff + 1024);
        Ap += 32; Bp += 32;
    };

    stage(pb0);
    stage(pb1);

    for (int k = 0; k < nk; ++k) {
        if (k + 2 < nk) {
            stage(pb2);
            asm volatile("s_waitcnt vmcnt(8)\ns_barrier" ::: "memory");
        } else if (k + 2 == nk) {
            asm volatile("s_waitcnt vmcnt(4)\ns_barrier" ::: "memory");
        } else {
            asm volatile("s_waitcnt vmcnt(0)\ns_barrier" ::: "memory");
        }
        unsigned char* Asb = pb0;
        unsigned char* Bsb = pb0 + 8192;
        bf16x8 af[4], bfr[4];
        #pragma unroll
        for (int mm = 0; mm < 4; ++mm)
            af[mm] = *reinterpret_cast<const bf16x8*>(Asb + (wr*4 + mm)*1024 + lane*16);
        #pragma unroll
        for (int nn = 0; nn < 4; ++nn)
            bfr[nn] = *reinterpret_cast<const bf16x8*>(Bsb + (wc*4 + nn)*1024 + lane*16);
        #pragma unroll
        for (int mm = 0; mm < 4; ++mm)
            #pragma unroll
            for (int nn = 0; nn < 4; ++nn)
                acc[mm][nn] = __builtin_amdgcn_mfma_f32_16x16x32_bf16(af[mm], bfr[nn], acc[mm][nn], 0, 0, 0);
        asm volatile("s_waitcnt lgkmcnt(0)\ns_barrier" ::: "memory");
        unsigned char* tp = pb0; pb0 = pb1; pb1 = pb2; pb2 = tp;
    }

    #pragma unroll
    for (int mm = 0; mm < 4; ++mm) {
        int row0 = bm + wr*64 + mm*16 + l4*4;
        #pragma unroll
        for (int nn = 0; nn < 4; ++nn) {
            int col = bn + wc*64 + nn*16 + l15;
            float bi = bias[col];
            #pragma unroll
            for (int r = 0; r < 4; ++r) {
                float v = acc[mm][nn][r] + bi;
                size_t idx = (size_t)(row0 + r) * N + col;
                if (EPI == 2) {
                    ((float*)Cv)[idx] = v + res[idx];
                } else {
                    v = 0.5f * v * (1.0f + erff(v * 0.70710678118654752f));
                    ((unsigned short*)Cv)[idx] = f2bf(v);
                }
            }
        }
    }
}

// ------------------------------------------------------- MFMA GEMM (256x256)
// 8 waves (2Mx4N), BK=64, double-buffered 128KiB LDS, counted vmcnt(8).
// Per K-step/wave: 64 MFMA vs 24 ds_read_b128 + 8 global_load_lds.
// Fragment-linear LDS: A = 32 x 1KB blocks [kc][mtile], within block
// [l4 kslot][l15 row]*16B; stage dest and frag read are base + lane*16.
// EPI: 1 = GELU -> bf16; 3 = qkv (Q/K bf16 row-major, V -> vt transposed).
template<int EPI>
__global__ __launch_bounds__(512, 2) void mgemm256(
    const unsigned short* __restrict__ A,
    const unsigned short* __restrict__ WT,
    const float* __restrict__ bias,
    void* Cv,
    unsigned short* __restrict__ vt,
    int M, int N, int K, int nbx)
{
    __shared__ __align__(16) unsigned char smem[131072];  // 2 x (A 32KB + B 32KB)
    int bid = blockIdx.x;
    int nwg = gridDim.x;
    int cpx = nwg >> 3;                                   // grids %8 == 0
    int swz = (bid & 7) * cpx + (bid >> 3);               // XCD-aware swizzle
    int bn = (swz % nbx) * 256;
    int bm = (swz / nbx) * 256;
    int t = threadIdx.x, lane = t & 63, w = t >> 6;       // w: 0..7
    int wr = w >> 2, wc = w & 3;                          // 2 x 4 waves
    int l15 = lane & 15, l4 = lane >> 4;

    const unsigned short* Ap0 = A  + (size_t)(bm + w*16 + l15) * K + 8*l4;
    const unsigned short* Ap1 = Ap0 + (size_t)128 * K;
    const unsigned short* Bp0 = WT + (size_t)(bn + w*16 + l15) * K + 8*l4;
    const unsigned short* Bp1 = Bp0 + (size_t)128 * K;
    unsigned aoff = w*1024 + lane*16;
    int koff = 0;

    f32x4 acc[8][4] = {};
    int nk = K >> 6;

    auto stage = [&](int buf) {
        unsigned char* Asb = smem + (buf << 16);
        unsigned char* Bsb = Asb + 32768;
        ldsload16(Ap0 + koff,      Asb + aoff);
        ldsload16(Ap1 + koff,      Asb + aoff + 8192);
        ldsload16(Ap0 + koff + 32, Asb + aoff + 16384);
        ldsload16(Ap1 + koff + 32, Asb + aoff + 24576);
        ldsload16(Bp0 + koff,      Bsb + aoff);
        ldsload16(Bp1 + koff,      Bsb + aoff + 8192);
        ldsload16(Bp0 + koff + 32, Bsb + aoff + 16384);
        ldsload16(Bp1 + koff + 32, Bsb + aoff + 24576);
        koff += 64;
    };

    stage(0);
    for (int k = 0; k < nk; ++k) {
        if (k + 1 < nk) {
            stage((k + 1) & 1);
            asm volatile("s_waitcnt vmcnt(8)\ns_barrier" ::: "memory");
        } else {
            asm volatile("s_waitcnt vmcnt(0)\ns_barrier" ::: "memory");
        }
        unsigned char* Asb = smem + ((k & 1) << 16);
        unsigned char* Bsb = Asb + 32768;
        #pragma unroll
        for (int kc = 0; kc < 2; ++kc) {
            bf16x8 af[8], bfr[4];
            #pragma unroll
            for (int mm = 0; mm < 8; ++mm)
                af[mm] = *reinterpret_cast<const bf16x8*>(Asb + kc*16384 + (wr*8 + mm)*1024 + lane*16);
            #pragma unroll
            for (int nn = 0; nn < 4; ++nn)
                bfr[nn] = *reinterpret_cast<const bf16x8*>(Bsb + kc*16384 + (wc*4 + nn)*1024 + lane*16);
            #pragma unroll
            for (int mm = 0; mm < 8; ++mm)
                #pragma unroll
                for (int nn = 0; nn < 4; ++nn)
                    acc[mm][nn] = __builtin_amdgcn_mfma_f32_16x16x32_bf16(af[mm], bfr[nn], acc[mm][nn], 0, 0, 0);
        }
        asm volatile("s_waitcnt lgkmcnt(0)\ns_barrier" ::: "memory");
    }

    bool isv = (EPI == 3) && (bn >= 2048);
    #pragma unroll
    for (int mm = 0; mm < 8; ++mm) {
        int row0 = bm + wr*128 + mm*16 + l4*4;
        #pragma unroll
        for (int nn = 0; nn < 4; ++nn) {
            int col = bn + wc*64 + nn*16 + l15;
            float bi = bias[col];
            #pragma unroll
            for (int r = 0; r < 4; ++r) {
                float v = acc[mm][nn][r] + bi;
                int row = row0 + r;
                size_t idx = (size_t)row * N + col;
                if (EPI == 1) {
                    v = 0.5f * v * (1.0f + erff(v * 0.70710678118654752f));
                    ((unsigned short*)Cv)[idx] = f2bf(v);
                } else { // EPI == 3
                    if (!isv) {
                        ((unsigned short*)Cv)[idx] = f2bf(v);
                    } else {
                        int bb = row >> 11, l = row & 2047;
                        int c2 = col - 2048, hh = c2 >> 6, dd = c2 & 63;
                        vt[((((size_t)(bb*HH + hh)*2 + (l & 1))*64 + dd) << 10) + (l >> 1)] = f2bf(v);
                    }
                }
            }
        }
    }
}

// ---------------------------------------------------------------- Attention
// Dilation-2 causal window == 2 independent causal sliding-window attentions
// (per parity), compressed length 1024, window 128 (+self). MFMA, 1 wave/blk.
__global__ __launch_bounds__(64, 1) void mattn(
    const unsigned short* __restrict__ qkvb,  // [4096][3072] bf16
    const unsigned short* __restrict__ vt,    // [b][h][p][64][1024] bf16
    unsigned short* __restrict__ o)           // [4096][1024] bf16
{
    __shared__ __align__(16) unsigned char PlB[8192];     // P tile, swizzled
    int qt = blockIdx.x, p = blockIdx.y, bh = blockIdx.z;
    int b = bh >> 4, h = bh & 15;
    int lane = threadIdx.x;
    int l15 = lane & 15, l4 = lane >> 4;

    bf16x8 qf[4][2];
    #pragma unroll
    for (int qb = 0; qb < 4; ++qb) {
        int tq = qt*64 + qb*16 + l15;
        const unsigned short* qr = qkvb + (size_t)(b*LL + 2*tq + p)*3072 + h*64 + 8*l4;
        qf[qb][0] = *reinterpret_cast<const bf16x8*>(qr);
        qf[qb][1] = *reinterpret_cast<const bf16x8*>(qr + 32);
    }

    float mreg[4], lreg[4];
    #pragma unroll
    for (int qb = 0; qb < 4; ++qb) { mreg[qb] = -1e30f; lreg[qb] = 0.f; }
    f32x4 oac[4][4] = {};   // [mt=d-tile][qb], O^T layout

    const unsigned short* vbase = vt + ((size_t)((b*HH + h)*2 + p) << 16);

    int kt0 = qt - 2; if (kt0 < 0) kt0 = 0;
    for (int kt = kt0; kt <= qt; ++kt) {
        bf16x8 kf[4][2], vf[4][2];
        #pragma unroll
        for (int kb = 0; kb < 4; ++kb) {
            const unsigned short* kr = qkvb + (size_t)(b*LL + 2*(kt*64 + kb*16 + l15) + p)*3072 + 1024 + h*64 + 8*l4;
            kf[kb][0] = *reinterpret_cast<const bf16x8*>(kr);
            kf[kb][1] = *reinterpret_cast<const bf16x8*>(kr + 32);
        }
        #pragma unroll
        for (int mt = 0; mt < 4; ++mt) {
            const unsigned short* vr = vbase + (mt*16 + l15)*1024 + kt*64 + 8*l4;
            vf[mt][0] = *reinterpret_cast<const bf16x8*>(vr);
            vf[mt][1] = *reinterpret_cast<const bf16x8*>(vr + 32);
        }
        f32x4 st[4][4];
        #pragma unroll
        for (int kb = 0; kb < 4; ++kb)
            #pragma unroll
            for (int qb = 0; qb < 4; ++qb) {
                f32x4 z = {0.f, 0.f, 0.f, 0.f};
                z = __builtin_amdgcn_mfma_f32_16x16x32_bf16(kf[kb][0], qf[qb][0], z, 0, 0, 0);
                st[kb][qb] = __builtin_amdgcn_mfma_f32_16x16x32_bf16(kf[kb][1], qf[qb][1], z, 0, 0, 0);
            }
        #pragma unroll
        for (int qb = 0; qb < 4; ++qb) {
            int tq = qt*64 + qb*16 + l15;
            int q = qb*16 + l15;
            float tmax = -1e30f;
            #pragma unroll
            for (int kb = 0; kb < 4; ++kb)
                #pragma unroll
                for (int r = 0; r < 4; ++r) {
                    int kc = kt*64 + kb*16 + 4*l4 + r;
                    float sv = st[kb][qb][r] * 0.125f;
                    sv = (kc + 128 >= tq && kc <= tq) ? sv : -1e30f;
                    st[kb][qb][r] = sv;
                    tmax = fmaxf(tmax, sv);
                }
            tmax = fmaxf(tmax, __shfl_xor(tmax, 16, 64));
            tmax = fmaxf(tmax, __shfl_xor(tmax, 32, 64));
            float newm = fmaxf(mreg[qb], tmax);
            float corr = __expf(mreg[qb] - newm);
            mreg[qb] = newm;
            float ps = 0.f;
            #pragma unroll
            for (int kb = 0; kb < 4; ++kb) {
                float p0 = __expf(st[kb][qb][0] - newm);
                float p1 = __expf(st[kb][qb][1] - newm);
                float p2 = __expf(st[kb][qb][2] - newm);
                float p3 = __expf(st[kb][qb][3] - newm);
                ps += (p0 + p1) + (p2 + p3);
                unsigned lo = (unsigned)f2bf(p0) | ((unsigned)f2bf(p1) << 16);
                unsigned hi = (unsigned)f2bf(p2) | ((unsigned)f2bf(p3) << 16);
                unsigned byteoff = ((unsigned)(q << 7) + (unsigned)(kb*32 + 8*l4)) ^ ((unsigned)(q & 7) << 4);
                *reinterpret_cast<uint2*>(PlB + byteoff) = make_uint2(lo, hi);
            }
            ps += __shfl_xor(ps, 16, 64);
            ps += __shfl_xor(ps, 32, 64);
            lreg[qb] = lreg[qb] * corr + ps;
            #pragma unroll
            for (int mt = 0; mt < 4; ++mt) {
                oac[mt][qb][0] *= corr; oac[mt][qb][1] *= corr;
                oac[mt][qb][2] *= corr; oac[mt][qb][3] *= corr;
            }
        }
        #pragma unroll
        for (int c = 0; c < 2; ++c)
            #pragma unroll
            for (int qb = 0; qb < 4; ++qb) {
                int q = qb*16 + l15;
                unsigned rb = ((unsigned)(q << 7) + (unsigned)(c*64 + 16*l4)) ^ ((unsigned)(q & 7) << 4);
                bf16x8 pf = *reinterpret_cast<const bf16x8*>(PlB + rb);
                #pragma unroll
                for (int mt = 0; mt < 4; ++mt)
                    oac[mt][qb] = __builtin_amdgcn_mfma_f32_16x16x32_bf16(vf[mt][c], pf, oac[mt][qb], 0, 0, 0);
            }
    }

    #pragma unroll
    for (int qb = 0; qb < 4; ++qb) {
        float inv = 1.f / lreg[qb];
        int tq = qt*64 + qb*16 + l15;
        unsigned short* orow = o + (size_t)(b*LL + 2*tq + p)*DD + h*64;
        #pragma unroll
        for (int mt = 0; mt < 4; ++mt) {
            int d0 = mt*16 + 4*l4;
            ushort4 o4;
            o4.x = f2bf(oac[mt][qb][0] * inv);
            o4.y = f2bf(oac[mt][qb][1] * inv);
            o4.z = f2bf(oac[mt][qb][2] * inv);
            o4.w = f2bf(oac[mt][qb][3] * inv);
            *reinterpret_cast<ushort4*>(orow + d0) = o4;
        }
    }
}

// ---------------------------------------------------------------- launch
extern "C" void kernel_launch(void* const* d_in, const int* in_sizes, int n_in,
                              void* d_out, int out_size, void* d_ws, size_t ws_size,
                              hipStream_t stream) {
    const float* x      = (const float*)d_in[0];
    const float* n1w    = (const float*)d_in[1];
    const float* n1b    = (const float*)d_in[2];
    const float* qkv_w  = (const float*)d_in[3];
    const float* qkv_b  = (const float*)d_in[4];
    const float* out_w  = (const float*)d_in[5];
    const float* out_b  = (const float*)d_in[6];
    const float* n2w    = (const float*)d_in[7];
    const float* n2b    = (const float*)d_in[8];
    const float* ffn_w1 = (const float*)d_in[9];
    const float* ffn_b1 = (const float*)d_in[10];
    const float* ffn_w2 = (const float*)d_in[11];
    const float* ffn_b2 = (const float*)d_in[12];

    unsigned char* wsb = (unsigned char*)d_ws;
    const size_t MB = 1024 * 1024;

    // ws layout (80MB):
    //  [0,24)  qkvb bf16  -+-> overlay after attn: mid bf16 [0,32)
    //  [24,32) vt bf16    -+
    //  [32,40) o_b bf16
    //  [40,48) xn bf16
    //  [48,56) hbuf bf16
    //  [56,80) weights bf16 transposed (qkvT 6, outT 2, w1T 8, w2T 8)
    unsigned short* qkvb = (unsigned short*)wsb;
    unsigned short* vt   = (unsigned short*)(wsb + 24*MB);
    unsigned short* mid  = (unsigned short*)wsb;
    unsigned short* o_b  = (unsigned short*)(wsb + 32*MB);
    unsigned short* xn   = (unsigned short*)(wsb + 40*MB);
    unsigned short* hbuf = (unsigned short*)(wsb + 48*MB);
    unsigned short* qkvT = (unsigned short*)(wsb + 56*MB);
    unsigned short* outT = (unsigned short*)(wsb + 62*MB);
    unsigned short* w1T  = (unsigned short*)(wsb + 64*MB);
    unsigned short* w2T  = (unsigned short*)(wsb + 72*MB);
    float*          y    = (float*)d_out;              // d_out doubles as y

    // 0. weight convert+transpose  fp32[K][N] -> bf16[N][K]
    convT_kernel<<<dim3(3*DD/64, DD/64), 256, 0, stream>>>(qkv_w,  qkvT, DD,  3*DD);
    convT_kernel<<<dim3(DD/64,   DD/64), 256, 0, stream>>>(out_w,  outT, DD,  DD);
    convT_kernel<<<dim3(HID/64,  DD/64), 256, 0, stream>>>(ffn_w1, w1T,  DD,  HID);
    convT_kernel<<<dim3(DD/64,  HID/64), 256, 0, stream>>>(ffn_w2, w2T,  HID, DD);

    // 1. xn = LN(x)                        (bf16)
    ln_kernel<<<MROWS, 256, 0, stream>>>(x, n1w, n1b, xn);
    // 2. qkv = xn @ qkv_w + qkv_b          (Q/K bf16 rowmajor, V -> vt)  [256²]
    mgemm256<3><<<(3*DD/256)*(MROWS/256), 512, 0, stream>>>(
        xn, qkvT, qkv_b, qkvb, vt, MROWS, 3*DD, DD, 3*DD/256);
    // 3. o = dilated-window attention      (bf16, MFMA)
    mattn<<<dim3(16, 2, BB*HH), 64, 0, stream>>>(qkvb, vt, o_b);
    // 4. y = x + o @ out_w + out_b         (fp32, in d_out)  [128²]
    mgemm<2><<<(DD/128)*(MROWS/128), 256, 0, stream>>>(
        o_b, outT, out_b, x, y, MROWS, DD, DD, DD/128);
    // 5. h = LN(y)                         (bf16)
    ln_kernel<<<MROWS, 256, 0, stream>>>(y, n2w, n2b, hbuf);
    // 6. mid = gelu(h @ ffn_w1 + b1)       (bf16)  [256²]
    mgemm256<1><<<(HID/256)*(MROWS/256), 512, 0, stream>>>(
        hbuf, w1T, ffn_b1, mid, nullptr, MROWS, HID, DD, HID/256);
    // 7. out = y + mid @ ffn_w2 + b2       (fp32, in-place over y)  [128²]
    mgemm<2><<<(DD/128)*(MROWS/128), 256, 0, stream>>>(
        mid, w2T, ffn_b2, y, y, MROWS, DD, HID, DD/128);
}

// Round 11
// 388.721 us; speedup vs baseline: 1.0412x; 1.0012x over previous
//
#include <hip/hip_runtime.h>
#include <math.h>

#define BB 2
#define LL 2048
#define DD 1024
#define HH 16
#define DH 64
#define HID 4096
#define MROWS (BB*LL)   // 4096

typedef __attribute__((ext_vector_type(8))) short bf16x8;
typedef __attribute__((ext_vector_type(4))) float f32x4;

__device__ __forceinline__ unsigned short f2bf(float f) {
    unsigned u = __builtin_bit_cast(unsigned, f);
    unsigned r = u + 0x7fffu + ((u >> 16) & 1u);
    return (unsigned short)(r >> 16);
}

__device__ __forceinline__ void ldsload16(const void* g, void* l) {
    __builtin_amdgcn_global_load_lds(
        (const __attribute__((address_space(1))) unsigned int*)g,
        (__attribute__((address_space(3))) unsigned int*)l,
        16, 0, 0);
}

// ------------------------------------------------- weight convert+transpose
// in: fp32 [K][N] row-major  ->  out: bf16 [N][K] row-major
__global__ __launch_bounds__(256) void convT_kernel(const float* __restrict__ in,
                                                    unsigned short* __restrict__ out,
                                                    int K, int N) {
    __shared__ float tile[64][65];
    int kt = blockIdx.y << 6, nt = blockIdx.x << 6;
    int t = threadIdx.x;
    int tr = t >> 4;            // 0..15
    int tc = (t & 15) << 2;     // 0,4,...,60
    #pragma unroll
    for (int i = 0; i < 4; ++i) {
        float4 v = *reinterpret_cast<const float4*>(&in[(size_t)(kt + i*16 + tr) * N + nt + tc]);
        tile[i*16 + tr][tc+0] = v.x;
        tile[i*16 + tr][tc+1] = v.y;
        tile[i*16 + tr][tc+2] = v.z;
        tile[i*16 + tr][tc+3] = v.w;
    }
    __syncthreads();
    #pragma unroll
    for (int i = 0; i < 4; ++i) {
        int n = i*16 + tr;
        ushort4 o4;
        o4.x = f2bf(tile[tc+0][n]);
        o4.y = f2bf(tile[tc+1][n]);
        o4.z = f2bf(tile[tc+2][n]);
        o4.w = f2bf(tile[tc+3][n]);
        *reinterpret_cast<ushort4*>(&out[(size_t)(nt + n) * K + kt + tc]) = o4;
    }
}

// ---------------------------------------------------------------- LayerNorm
// fp32 in -> bf16 out
__global__ __launch_bounds__(256) void ln_kernel(const float* __restrict__ in,
                                                 const float* __restrict__ w,
                                                 const float* __restrict__ b,
                                                 unsigned short* __restrict__ out) {
    int row = blockIdx.x;
    const float* x = in + (size_t)row * DD;
    unsigned short* o = out + (size_t)row * DD;
    int t = threadIdx.x;
    float4 v = reinterpret_cast<const float4*>(x)[t];
    float s  = v.x + v.y + v.z + v.w;
    float ss = v.x*v.x + v.y*v.y + v.z*v.z + v.w*v.w;
    #pragma unroll
    for (int off = 32; off > 0; off >>= 1) {
        s  += __shfl_down(s,  off, 64);
        ss += __shfl_down(ss, off, 64);
    }
    __shared__ float red[8];
    int wid = t >> 6, lane = t & 63;
    if (lane == 0) { red[wid] = s; red[4 + wid] = ss; }
    __syncthreads();
    if (t == 0) {
        float S  = red[0] + red[1] + red[2] + red[3];
        float SS = red[4] + red[5] + red[6] + red[7];
        float mean = S / DD;
        float var  = SS / DD - mean * mean;
        red[0] = mean;
        red[1] = rsqrtf(var + 1e-5f);
    }
    __syncthreads();
    float mean = red[0], rstd = red[1];
    float4 wv = reinterpret_cast<const float4*>(w)[t];
    float4 bv = reinterpret_cast<const float4*>(b)[t];
    ushort4 ov;
    ov.x = f2bf((v.x - mean) * rstd * wv.x + bv.x);
    ov.y = f2bf((v.y - mean) * rstd * wv.y + bv.y);
    ov.z = f2bf((v.z - mean) * rstd * wv.z + bv.z);
    ov.w = f2bf((v.w - mean) * rstd * wv.w + bv.w);
    reinterpret_cast<ushort4*>(o)[t] = ov;
}

// ------------------------------------------------------- MFMA GEMM (128x128)
// For N=1024 GEMMs (grid 256 blocks). EPI 2 = fp32 out + res.
// BK=64: 32 MFMA between barriers (2x the old BK=32), halving the number of
// per-step barrier/latency floors. Triple-buffered (3 x 32KB), 2-deep
// prefetch, counted vmcnt(16/8/0). Fragment-linear LDS: per buffer
// [A kc0 8K][A kc1 8K][B kc0 8K][B kc1 8K]; stage dest and ds_read frag
// are both base + lane*16 (conflict-free).
template<int EPI>
__global__ __launch_bounds__(256) void mgemm(
    const unsigned short* __restrict__ A,
    const unsigned short* __restrict__ WT,
    const float* __restrict__ bias,
    const float* res, void* Cv,
    int M, int N, int K, int nbx)
{
    __shared__ __align__(16) unsigned char smem[98304];   // 3 x 32KB
    int bid = blockIdx.x;
    int nwg = gridDim.x;
    int cpx = nwg >> 3;                                   // grids %8 == 0
    int swz = (bid & 7) * cpx + (bid >> 3);               // XCD-aware swizzle
    int bn = (swz % nbx) * 128;
    int bm = (swz / nbx) * 128;
    int t = threadIdx.x, lane = t & 63, w = t >> 6;
    int wr = w >> 1, wc = w & 1;
    int l15 = lane & 15, l4 = lane >> 4;

    const unsigned short* Ap = A  + (size_t)(bm + w*32 + l15) * K + 8*l4;
    const unsigned short* Bp = WT + (size_t)(bn + w*32 + l15) * K + 8*l4;
    unsigned stoff = w*2048 + lane*16;

    f32x4 acc[4][4] = {};
    int nk = K >> 6;

    unsigned char* pb0 = smem;
    unsigned char* pb1 = smem + 32768;
    unsigned char* pb2 = smem + 65536;

    auto stage = [&](unsigned char* bs) {
        ldsload16(Ap,             bs + stoff);                 // A kc0 rows w*32..
        ldsload16(Ap + 16*K,      bs + stoff + 1024);          // A kc0 rows +16
        ldsload16(Ap + 32,        bs + 8192 + stoff);          // A kc1
        ldsload16(Ap + 16*K + 32, bs + 8192 + stoff + 1024);
        ldsload16(Bp,             bs + 16384 + stoff);         // B kc0
        ldsload16(Bp + 16*K,      bs + 16384 + stoff + 1024);
        ldsload16(Bp + 32,        bs + 24576 + stoff);         // B kc1
        ldsload16(Bp + 16*K + 32, bs + 24576 + stoff + 1024);
        Ap += 64; Bp += 64;
    };

    stage(pb0);
    stage(pb1);

    for (int k = 0; k < nk; ++k) {
        if (k + 2 < nk) {
            stage(pb2);
            asm volatile("s_waitcnt vmcnt(16)\ns_barrier" ::: "memory");
        } else if (k + 2 == nk) {
            asm volatile("s_waitcnt vmcnt(8)\ns_barrier" ::: "memory");
        } else {
            asm volatile("s_waitcnt vmcnt(0)\ns_barrier" ::: "memory");
        }
        unsigned char* Asb = pb0;
        unsigned char* Bsb = pb0 + 16384;
        #pragma unroll
        for (int kc = 0; kc < 2; ++kc) {
            bf16x8 af[4], bfr[4];
            #pragma unroll
            for (int mm = 0; mm < 4; ++mm)
                af[mm] = *reinterpret_cast<const bf16x8*>(Asb + kc*8192 + (wr*4 + mm)*1024 + lane*16);
            #pragma unroll
            for (int nn = 0; nn < 4; ++nn)
                bfr[nn] = *reinterpret_cast<const bf16x8*>(Bsb + kc*8192 + (wc*4 + nn)*1024 + lane*16);
            #pragma unroll
            for (int mm = 0; mm < 4; ++mm)
                #pragma unroll
                for (int nn = 0; nn < 4; ++nn)
                    acc[mm][nn] = __builtin_amdgcn_mfma_f32_16x16x32_bf16(af[mm], bfr[nn], acc[mm][nn], 0, 0, 0);
        }
        asm volatile("s_waitcnt lgkmcnt(0)\ns_barrier" ::: "memory");
        unsigned char* tp = pb0; pb0 = pb1; pb1 = pb2; pb2 = tp;
    }

    #pragma unroll
    for (int mm = 0; mm < 4; ++mm) {
        int row0 = bm + wr*64 + mm*16 + l4*4;
        #pragma unroll
        for (int nn = 0; nn < 4; ++nn) {
            int col = bn + wc*64 + nn*16 + l15;
            float bi = bias[col];
            #pragma unroll
            for (int r = 0; r < 4; ++r) {
                float v = acc[mm][nn][r] + bi;
                size_t idx = (size_t)(row0 + r) * N + col;
                if (EPI == 2) {
                    ((float*)Cv)[idx] = v + res[idx];
                } else {
                    v = 0.5f * v * (1.0f + erff(v * 0.70710678118654752f));
                    ((unsigned short*)Cv)[idx] = f2bf(v);
                }
            }
        }
    }
}

// ------------------------------------------------------- MFMA GEMM (256x256)
// 8 waves (2Mx4N), BK=64, double-buffered 128KiB LDS, counted vmcnt(8).
// EPI: 1 = GELU -> bf16; 3 = qkv (Q/K bf16 row-major, V -> vt transposed).
template<int EPI>
__global__ __launch_bounds__(512, 2) void mgemm256(
    const unsigned short* __restrict__ A,
    const unsigned short* __restrict__ WT,
    const float* __restrict__ bias,
    void* Cv,
    unsigned short* __restrict__ vt,
    int M, int N, int K, int nbx)
{
    __shared__ __align__(16) unsigned char smem[131072];  // 2 x (A 32KB + B 32KB)
    int bid = blockIdx.x;
    int nwg = gridDim.x;
    int cpx = nwg >> 3;                                   // grids %8 == 0
    int swz = (bid & 7) * cpx + (bid >> 3);               // XCD-aware swizzle
    int bn = (swz % nbx) * 256;
    int bm = (swz / nbx) * 256;
    int t = threadIdx.x, lane = t & 63, w = t >> 6;       // w: 0..7
    int wr = w >> 2, wc = w & 3;                          // 2 x 4 waves
    int l15 = lane & 15, l4 = lane >> 4;

    const unsigned short* Ap0 = A  + (size_t)(bm + w*16 + l15) * K + 8*l4;
    const unsigned short* Ap1 = Ap0 + (size_t)128 * K;
    const unsigned short* Bp0 = WT + (size_t)(bn + w*16 + l15) * K + 8*l4;
    const unsigned short* Bp1 = Bp0 + (size_t)128 * K;
    unsigned aoff = w*1024 + lane*16;
    int koff = 0;

    f32x4 acc[8][4] = {};
    int nk = K >> 6;

    auto stage = [&](int buf) {
        unsigned char* Asb = smem + (buf << 16);
        unsigned char* Bsb = Asb + 32768;
        ldsload16(Ap0 + koff,      Asb + aoff);
        ldsload16(Ap1 + koff,      Asb + aoff + 8192);
        ldsload16(Ap0 + koff + 32, Asb + aoff + 16384);
        ldsload16(Ap1 + koff + 32, Asb + aoff + 24576);
        ldsload16(Bp0 + koff,      Bsb + aoff);
        ldsload16(Bp1 + koff,      Bsb + aoff + 8192);
        ldsload16(Bp0 + koff + 32, Bsb + aoff + 16384);
        ldsload16(Bp1 + koff + 32, Bsb + aoff + 24576);
        koff += 64;
    };

    stage(0);
    for (int k = 0; k < nk; ++k) {
        if (k + 1 < nk) {
            stage((k + 1) & 1);
            asm volatile("s_waitcnt vmcnt(8)\ns_barrier" ::: "memory");
        } else {
            asm volatile("s_waitcnt vmcnt(0)\ns_barrier" ::: "memory");
        }
        unsigned char* Asb = smem + ((k & 1) << 16);
        unsigned char* Bsb = Asb + 32768;
        #pragma unroll
        for (int kc = 0; kc < 2; ++kc) {
            bf16x8 af[8], bfr[4];
            #pragma unroll
            for (int mm = 0; mm < 8; ++mm)
                af[mm] = *reinterpret_cast<const bf16x8*>(Asb + kc*16384 + (wr*8 + mm)*1024 + lane*16);
            #pragma unroll
            for (int nn = 0; nn < 4; ++nn)
                bfr[nn] = *reinterpret_cast<const bf16x8*>(Bsb + kc*16384 + (wc*4 + nn)*1024 + lane*16);
            #pragma unroll
            for (int mm = 0; mm < 8; ++mm)
                #pragma unroll
                for (int nn = 0; nn < 4; ++nn)
                    acc[mm][nn] = __builtin_amdgcn_mfma_f32_16x16x32_bf16(af[mm], bfr[nn], acc[mm][nn], 0, 0, 0);
        }
        asm volatile("s_waitcnt lgkmcnt(0)\ns_barrier" ::: "memory");
    }

    bool isv = (EPI == 3) && (bn >= 2048);
    #pragma unroll
    for (int mm = 0; mm < 8; ++mm) {
        int row0 = bm + wr*128 + mm*16 + l4*4;
        #pragma unroll
        for (int nn = 0; nn < 4; ++nn) {
            int col = bn + wc*64 + nn*16 + l15;
            float bi = bias[col];
            #pragma unroll
            for (int r = 0; r < 4; ++r) {
                float v = acc[mm][nn][r] + bi;
                int row = row0 + r;
                size_t idx = (size_t)row * N + col;
                if (EPI == 1) {
                    v = 0.5f * v * (1.0f + erff(v * 0.70710678118654752f));
                    ((unsigned short*)Cv)[idx] = f2bf(v);
                } else { // EPI == 3
                    if (!isv) {
                        ((unsigned short*)Cv)[idx] = f2bf(v);
                    } else {
                        int bb = row >> 11, l = row & 2047;
                        int c2 = col - 2048, hh = c2 >> 6, dd = c2 & 63;
                        vt[((((size_t)(bb*HH + hh)*2 + (l & 1))*64 + dd) << 10) + (l >> 1)] = f2bf(v);
                    }
                }
            }
        }
    }
}

// ---------------------------------------------------------------- Attention
// Dilation-2 causal window == 2 independent causal sliding-window attentions
// (per parity), compressed length 1024, window 128 (+self). MFMA, 1 wave/blk.
__global__ __launch_bounds__(64, 1) void mattn(
    const unsigned short* __restrict__ qkvb,  // [4096][3072] bf16
    const unsigned short* __restrict__ vt,    // [b][h][p][64][1024] bf16
    unsigned short* __restrict__ o)           // [4096][1024] bf16
{
    __shared__ __align__(16) unsigned char PlB[8192];     // P tile, swizzled
    int qt = blockIdx.x, p = blockIdx.y, bh = blockIdx.z;
    int b = bh >> 4, h = bh & 15;
    int lane = threadIdx.x;
    int l15 = lane & 15, l4 = lane >> 4;

    bf16x8 qf[4][2];
    #pragma unroll
    for (int qb = 0; qb < 4; ++qb) {
        int tq = qt*64 + qb*16 + l15;
        const unsigned short* qr = qkvb + (size_t)(b*LL + 2*tq + p)*3072 + h*64 + 8*l4;
        qf[qb][0] = *reinterpret_cast<const bf16x8*>(qr);
        qf[qb][1] = *reinterpret_cast<const bf16x8*>(qr + 32);
    }

    float mreg[4], lreg[4];
    #pragma unroll
    for (int qb = 0; qb < 4; ++qb) { mreg[qb] = -1e30f; lreg[qb] = 0.f; }
    f32x4 oac[4][4] = {};   // [mt=d-tile][qb], O^T layout

    const unsigned short* vbase = vt + ((size_t)((b*HH + h)*2 + p) << 16);

    int kt0 = qt - 2; if (kt0 < 0) kt0 = 0;
    for (int kt = kt0; kt <= qt; ++kt) {
        bf16x8 kf[4][2], vf[4][2];
        #pragma unroll
        for (int kb = 0; kb < 4; ++kb) {
            const unsigned short* kr = qkvb + (size_t)(b*LL + 2*(kt*64 + kb*16 + l15) + p)*3072 + 1024 + h*64 + 8*l4;
            kf[kb][0] = *reinterpret_cast<const bf16x8*>(kr);
            kf[kb][1] = *reinterpret_cast<const bf16x8*>(kr + 32);
        }
        #pragma unroll
        for (int mt = 0; mt < 4; ++mt) {
            const unsigned short* vr = vbase + (mt*16 + l15)*1024 + kt*64 + 8*l4;
            vf[mt][0] = *reinterpret_cast<const bf16x8*>(vr);
            vf[mt][1] = *reinterpret_cast<const bf16x8*>(vr + 32);
        }
        f32x4 st[4][4];
        #pragma unroll
        for (int kb = 0; kb < 4; ++kb)
            #pragma unroll
            for (int qb = 0; qb < 4; ++qb) {
                f32x4 z = {0.f, 0.f, 0.f, 0.f};
                z = __builtin_amdgcn_mfma_f32_16x16x32_bf16(kf[kb][0], qf[qb][0], z, 0, 0, 0);
                st[kb][qb] = __builtin_amdgcn_mfma_f32_16x16x32_bf16(kf[kb][1], qf[qb][1], z, 0, 0, 0);
            }
        #pragma unroll
        for (int qb = 0; qb < 4; ++qb) {
            int tq = qt*64 + qb*16 + l15;
            int q = qb*16 + l15;
            float tmax = -1e30f;
            #pragma unroll
            for (int kb = 0; kb < 4; ++kb)
                #pragma unroll
                for (int r = 0; r < 4; ++r) {
                    int kc = kt*64 + kb*16 + 4*l4 + r;
                    float sv = st[kb][qb][r] * 0.125f;
                    sv = (kc + 128 >= tq && kc <= tq) ? sv : -1e30f;
                    st[kb][qb][r] = sv;
                    tmax = fmaxf(tmax, sv);
                }
            tmax = fmaxf(tmax, __shfl_xor(tmax, 16, 64));
            tmax = fmaxf(tmax, __shfl_xor(tmax, 32, 64));
            float newm = fmaxf(mreg[qb], tmax);
            float corr = __expf(mreg[qb] - newm);
            mreg[qb] = newm;
            float ps = 0.f;
            #pragma unroll
            for (int kb = 0; kb < 4; ++kb) {
                float p0 = __expf(st[kb][qb][0] - newm);
                float p1 = __expf(st[kb][qb][1] - newm);
                float p2 = __expf(st[kb][qb][2] - newm);
                float p3 = __expf(st[kb][qb][3] - newm);
                ps += (p0 + p1) + (p2 + p3);
                unsigned lo = (unsigned)f2bf(p0) | ((unsigned)f2bf(p1) << 16);
                unsigned hi = (unsigned)f2bf(p2) | ((unsigned)f2bf(p3) << 16);
                unsigned byteoff = ((unsigned)(q << 7) + (unsigned)(kb*32 + 8*l4)) ^ ((unsigned)(q & 7) << 4);
                *reinterpret_cast<uint2*>(PlB + byteoff) = make_uint2(lo, hi);
            }
            ps += __shfl_xor(ps, 16, 64);
            ps += __shfl_xor(ps, 32, 64);
            lreg[qb] = lreg[qb] * corr + ps;
            #pragma unroll
            for (int mt = 0; mt < 4; ++mt) {
                oac[mt][qb][0] *= corr; oac[mt][qb][1] *= corr;
                oac[mt][qb][2] *= corr; oac[mt][qb][3] *= corr;
            }
        }
        #pragma unroll
        for (int c = 0; c < 2; ++c)
            #pragma unroll
            for (int qb = 0; qb < 4; ++qb) {
                int q = qb*16 + l15;
                unsigned rb = ((unsigned)(q << 7) + (unsigned)(c*64 + 16*l4)) ^ ((unsigned)(q & 7) << 4);
                bf16x8 pf = *reinterpret_cast<const bf16x8*>(PlB + rb);
                #pragma unroll
                for (int mt = 0; mt < 4; ++mt)
                    oac[mt][qb] = __builtin_amdgcn_mfma_f32_16x16x32_bf16(vf[mt][c], pf, oac[mt][qb], 0, 0, 0);
            }
    }

    #pragma unroll
    for (int qb = 0; qb < 4; ++qb) {
        float inv = 1.f / lreg[qb];
        int tq = qt*64 + qb*16 + l15;
        unsigned short* orow = o + (size_t)(b*LL + 2*tq + p)*DD + h*64;
        #pragma unroll
        for (int mt = 0; mt < 4; ++mt) {
            int d0 = mt*16 + 4*l4;
            ushort4 o4;
            o4.x = f2bf(oac[mt][qb][0] * inv);
            o4.y = f2bf(oac[mt][qb][1] * inv);
            o4.z = f2bf(oac[mt][qb][2] * inv);
            o4.w = f2bf(oac[mt][qb][3] * inv);
            *reinterpret_cast<ushort4*>(orow + d0) = o4;
        }
    }
}

// ---------------------------------------------------------------- launch
extern "C" void kernel_launch(void* const* d_in, const int* in_sizes, int n_in,
                              void* d_out, int out_size, void* d_ws, size_t ws_size,
                              hipStream_t stream) {
    const float* x      = (const float*)d_in[0];
    const float* n1w    = (const float*)d_in[1];
    const float* n1b    = (const float*)d_in[2];
    const float* qkv_w  = (const float*)d_in[3];
    const float* qkv_b  = (const float*)d_in[4];
    const float* out_w  = (const float*)d_in[5];
    const float* out_b  = (const float*)d_in[6];
    const float* n2w    = (const float*)d_in[7];
    const float* n2b    = (const float*)d_in[8];
    const float* ffn_w1 = (const float*)d_in[9];
    const float* ffn_b1 = (const float*)d_in[10];
    const float* ffn_w2 = (const float*)d_in[11];
    const float* ffn_b2 = (const float*)d_in[12];

    unsigned char* wsb = (unsigned char*)d_ws;
    const size_t MB = 1024 * 1024;

    // ws layout (80MB):
    //  [0,24)  qkvb bf16  -+-> overlay after attn: mid bf16 [0,32)
    //  [24,32) vt bf16    -+
    //  [32,40) o_b bf16
    //  [40,48) xn bf16
    //  [48,56) hbuf bf16
    //  [56,80) weights bf16 transposed (qkvT 6, outT 2, w1T 8, w2T 8)
    unsigned short* qkvb = (unsigned short*)wsb;
    unsigned short* vt   = (unsigned short*)(wsb + 24*MB);
    unsigned short* mid  = (unsigned short*)wsb;
    unsigned short* o_b  = (unsigned short*)(wsb + 32*MB);
    unsigned short* xn   = (unsigned short*)(wsb + 40*MB);
    unsigned short* hbuf = (unsigned short*)(wsb + 48*MB);
    unsigned short* qkvT = (unsigned short*)(wsb + 56*MB);
    unsigned short* outT = (unsigned short*)(wsb + 62*MB);
    unsigned short* w1T  = (unsigned short*)(wsb + 64*MB);
    unsigned short* w2T  = (unsigned short*)(wsb + 72*MB);
    float*          y    = (float*)d_out;              // d_out doubles as y

    // 0. weight convert+transpose  fp32[K][N] -> bf16[N][K]
    convT_kernel<<<dim3(3*DD/64, DD/64), 256, 0, stream>>>(qkv_w,  qkvT, DD,  3*DD);
    convT_kernel<<<dim3(DD/64,   DD/64), 256, 0, stream>>>(out_w,  outT, DD,  DD);
    convT_kernel<<<dim3(HID/64,  DD/64), 256, 0, stream>>>(ffn_w1, w1T,  DD,  HID);
    convT_kernel<<<dim3(DD/64,  HID/64), 256, 0, stream>>>(ffn_w2, w2T,  HID, DD);

    // 1. xn = LN(x)                        (bf16)
    ln_kernel<<<MROWS, 256, 0, stream>>>(x, n1w, n1b, xn);
    // 2. qkv = xn @ qkv_w + qkv_b          (Q/K bf16 rowmajor, V -> vt)  [256²]
    mgemm256<3><<<(3*DD/256)*(MROWS/256), 512, 0, stream>>>(
        xn, qkvT, qkv_b, qkvb, vt, MROWS, 3*DD, DD, 3*DD/256);
    // 3. o = dilated-window attention      (bf16, MFMA)
    mattn<<<dim3(16, 2, BB*HH), 64, 0, stream>>>(qkvb, vt, o_b);
    // 4. y = x + o @ out_w + out_b         (fp32, in d_out)  [128² BK=64]
    mgemm<2><<<(DD/128)*(MROWS/128), 256, 0, stream>>>(
        o_b, outT, out_b, x, y, MROWS, DD, DD, DD/128);
    // 5. h = LN(y)                         (bf16)
    ln_kernel<<<MROWS, 256, 0, stream>>>(y, n2w, n2b, hbuf);
    // 6. mid = gelu(h @ ffn_w1 + b1)       (bf16)  [256²]
    mgemm256<1><<<(HID/256)*(MROWS/256), 512, 0, stream>>>(
        hbuf, w1T, ffn_b1, mid, nullptr, MROWS, HID, DD, HID/256);
    // 7. out = y + mid @ ffn_w2 + b2       (fp32, in-place over y)  [128² BK=64]
    mgemm<2><<<(DD/128)*(MROWS/128), 256, 0, stream>>>(
        mid, w2T, ffn_b2, y, y, MROWS, DD, HID, DD/128);
}